// Round 8
// baseline (235.437 us; speedup 1.0000x reference)
//
#include <hip/hip_runtime.h>
#include <math.h>

// TreeAttention: hierarchical top-k mask refinement + sparse attention.
// N=8, T_DST=512, T_SRC=4096, HID=64, K=64, W0=64, SCALE_UP=2, OVERSAMPLE=1.5
//
// Round 8: LATENCY BATCHING. Round 7 showed the grid is fully resident
// (4 blocks/CU, 16 waves/CU) and dur == per-wave serial latency, 12x the
// VALU work -> serialized loads (VGPR=60 starved the scheduler). Fix:
//  - dot_f32 loads the whole k row into float4 kr[16] (one waitcnt).
//  - rank loop reads keys in 8-deep uint4 batches.
//  - PV loop reads (p,pix) and v in 8-deep batches.
//  - __launch_bounds__(256,4): 128-VGPR budget, free at 4 blocks/CU.
// Structure unchanged: 4 rows/block, one row per wave, private LDS slices,
// wave_barrier only (no inter-wave sync).

#define TSRC_N 4096
#define HID_N  64
#define NEGV   -32000.0f

__global__ __launch_bounds__(256, 4)
void tree_attn_kernel(const float* __restrict__ q,
                      const float* __restrict__ k,
                      const float* __restrict__ v,
                      float* __restrict__ out)
{
    // wave-uniform wave id (readfirstlane keeps row uniform -> q s_load)
    const int wid  = __builtin_amdgcn_readfirstlane((int)(threadIdx.x >> 6));
    const int lane = threadIdx.x & 63;
    const int row  = (blockIdx.x << 2) + wid;        // 0..4095, wave-uniform
    const int n    = row >> 9;
    const float tsrc = (float)(3585 + (row & 511));

    // per-wave private LDS slices — no cross-wave sharing, no __syncthreads
    __shared__ __align__(16) unsigned int key_s[4][128];
    __shared__ __align__(16) unsigned int bm[4][128];   // 4096-bit bitmaps
    __shared__ int                        pix_s[4][128];
    __shared__ unsigned char              msk_s[4][128];
    __shared__ __align__(8) unsigned int  pp_s[4][128]; // {p_bits, pix} pairs
    unsigned int* const keyw = key_s[wid];
    unsigned int* const bmw  = bm[wid];
    int* const           pixw = pix_s[wid];
    unsigned char* const mskw = msk_s[wid];
    unsigned int* const  ppw  = pp_s[wid];

    const float* qrow = q + (size_t)row * HID_N;     // uniform -> s_load
    const float* kb   = k + (size_t)n * TSRC_N * HID_N;
    const float* vb   = v + (size_t)n * TSRC_N * HID_N;

    // f32 dot: batch-load the whole k row (16x float4 in flight), then FMA.
    auto dot_f32 = [&](int tx) -> float {
        const float4* k4 = (const float4*)(kb + (size_t)tx * HID_N);
        float4 kr[16];
        #pragma unroll
        for (int h = 0; h < 16; ++h) kr[h] = k4[h];   // static idx -> regs
        float a0 = 0.f, a1 = 0.f, a2 = 0.f, a3 = 0.f;
        #pragma unroll
        for (int h = 0; h < 16; ++h) {
            a0 = fmaf(kr[h].x, qrow[h * 4 + 0], a0);
            a1 = fmaf(kr[h].y, qrow[h * 4 + 1], a1);
            a2 = fmaf(kr[h].z, qrow[h * 4 + 2], a2);
            a3 = fmaf(kr[h].w, qrow[h * 4 + 3], a3);
        }
        return (a0 + a1) + (a2 + a3);
    };
    // order-preserving f32 -> u32 flip (key 0 reserved for absent slots)
    auto flip32 = [](float s) -> unsigned int {
        const unsigned int u = __float_as_uint(s);
        return u ^ ((unsigned)((int)u >> 31) | 0x80000000u);
    };

    // iteration 0 state: pixels = arange(96), pmask = arange(96) < 64
    pixw[lane]      = lane;
    pixw[lane + 64] = lane + 64;
    mskw[lane]      = 1;
    mskw[lane + 64] = 0;
    __builtin_amdgcn_wave_barrier();

    float ws = 64.0f;
    int Z = 96;

    for (int it = 0; it < 7; ++it) {
        const bool  last    = (it == 6);
        const float mult    = last ? 1.0f : 1.5f;
        const int   tks_max = (it == 0) ? 63 : (last ? 64 : 96);
        const int   max_z   = last ? 64 : 128;
        const int   e1      = lane + 64;

        // ---- scores -> u32 keys (two elements per lane) ----
        const float r = tsrc / ws;                 // exact f32 (pow2 ratio or 1)
        unsigned int key0 = 0, key1 = 0;
        {
            float s0 = NEGV;
            if (mskw[lane]) {
                int tx = (int)rintf((float)pixw[lane] * r);
                tx = tx < (TSRC_N - 1) ? tx : (TSRC_N - 1);
                s0 = dot_f32(tx);
            }
            key0 = flip32(s0);
        }
        if (e1 < Z) {
            float s1 = NEGV;
            if (mskw[e1]) {
                int tx = (int)rintf((float)pixw[e1] * r);
                tx = tx < (TSRC_N - 1) ? tx : (TSRC_N - 1);
                s1 = dot_f32(tx);
            }
            key1 = flip32(s1);
        }
        keyw[lane] = key0;
        keyw[e1]   = key1;
        bmw[lane]  = 0u;
        bmw[e1]    = 0u;
        __builtin_amdgcn_wave_barrier();

        // ---- ranks: 8-deep batched uint4 key reads, both elements/lane ----
        int r0 = 0, r1 = 0;
        #pragma unroll
        for (int j = 0; j < 128; j += 32) {
            uint4 kk[8];
            #pragma unroll
            for (int t = 0; t < 8; ++t)
                kk[t] = *(const uint4*)&keyw[j + 4 * t];
            #pragma unroll
            for (int t = 0; t < 8; ++t) {
                r0 += (int)(kk[t].x > key0) + (int)(kk[t].y > key0)
                    + (int)(kk[t].z > key0) + (int)(kk[t].w > key0);
                r1 += (int)(kk[t].x > key1) + (int)(kk[t].y > key1)
                    + (int)(kk[t].z > key1) + (int)(kk[t].w > key1);
            }
        }

        // ---- tks = clip(round(ws/tsrc * 64 * mult), 1, min(ws-1, Z-1)) ----
        float x = ws / tsrc;
        x *= 64.0f;
        x *= mult;
        float t = rintf(x);
        t = fmaxf(1.0f, fminf(t, fminf(ws - 1.0f, (float)(Z - 1))));
        const int tks = (int)t;

        const float ws_new = fminf(tsrc, ws * 2.0f);
        const float scale  = ws_new / ws;     // 2.0, tsrc/2048, or 1.0 (exact)

        // ---- scatter next-scale values into the bitmap ----
        if (lane == 0) atomicOr(&bmw[0], 1u); // padded top-k slots -> value 0
        if (r0 < tks_max) {
            const int p  = pixw[lane];
            int s0 = (int)rintf((float)p * scale);
            s0 = s0 < (TSRC_N - 1) ? s0 : (TSRC_N - 1);
            atomicOr(&bmw[s0 >> 5], 1u << (s0 & 31));
            if (r0 < tks) {
                const int s1i = (int)rintf((float)(p + 1) * scale);
                if (s1i - s0 >= 2) {
                    const int c = s0 + 1;
                    atomicOr(&bmw[c >> 5], 1u << (c & 31));
                }
            }
        }
        if (e1 < Z && r1 < tks_max) {
            const int p  = pixw[e1];
            int s0 = (int)rintf((float)p * scale);
            s0 = s0 < (TSRC_N - 1) ? s0 : (TSRC_N - 1);
            atomicOr(&bmw[s0 >> 5], 1u << (s0 & 31));
            if (r1 < tks) {
                const int s1i = (int)rintf((float)(p + 1) * scale);
                if (s1i - s0 >= 2) {
                    const int c = s0 + 1;
                    atomicOr(&bmw[c >> 5], 1u << (c & 31));
                }
            }
        }
        __builtin_amdgcn_wave_barrier();

        // ---- exclusive prefix of popcounts; lane owns words 2L, 2L+1 ----
        const uint2 w2 = *(const uint2*)&bmw[2 * lane];
        const int c = __popc(w2.x) + __popc(w2.y);
        int scan = c;
        #pragma unroll
        for (int off = 1; off < 64; off <<= 1) {
            const int o = __shfl_up(scan, off);
            if (lane >= off) scan += o;
        }
        int pref = scan - c;                  // exclusive prefix
        pixw[lane] = 0;  pixw[e1] = 0;
        mskw[lane] = 0;  mskw[e1] = 0;
        __builtin_amdgcn_wave_barrier();

        // ---- enumerate ascending set bits == sort+dedup, first max_z ----
        unsigned int wv = w2.x;
        int base = lane << 6;                 // word 2L covers values 64L..
        while (wv) {
            if (pref >= max_z) break;
            const int b = __ffs(wv) - 1;
            wv &= wv - 1u;
            pixw[pref] = base + b;
            mskw[pref] = 1;
            ++pref;
        }
        wv = w2.y;
        base += 32;
        while (wv) {
            if (pref >= max_z) break;
            const int b = __ffs(wv) - 1;
            wv &= wv - 1u;
            pixw[pref] = base + b;
            mskw[pref] = 1;
            ++pref;
        }
        __builtin_amdgcn_wave_barrier();

        ws = ws_new;
        Z  = max_z;
    }

    // ---- final attention over the 64 selected pixels (f32, matches ref) ----
    {
        const int pix = pixw[lane];
        float sfin = -1e30f;
        if (mskw[lane]) sfin = dot_f32(pix);
        float m = sfin;
        #pragma unroll
        for (int off = 32; off > 0; off >>= 1)
            m = fmaxf(m, __shfl_xor(m, off));
        const float e = __expf(sfin - m);     // masked -> 0
        float ssum = e;
        #pragma unroll
        for (int off = 32; off > 0; off >>= 1)
            ssum += __shfl_xor(ssum, off);
        const float p = e / ssum;
        ppw[2 * lane]     = __float_as_uint(p);
        ppw[2 * lane + 1] = (unsigned int)pix;
    }
    __builtin_amdgcn_wave_barrier();

    // ---- PV: 8-deep batched (p,pix) + v loads ----
    {
        float acc = 0.f;
        #pragma unroll
        for (int j0 = 0; j0 < 64; j0 += 8) {
            uint2 pp[8];
            #pragma unroll
            for (int t = 0; t < 8; ++t)
                pp[t] = *(const uint2*)&ppw[2 * (j0 + t)];
            float vl[8];
            #pragma unroll
            for (int t = 0; t < 8; ++t)
                vl[t] = vb[(size_t)pp[t].y * HID_N + lane];
            #pragma unroll
            for (int t = 0; t < 8; ++t)
                acc = fmaf(__uint_as_float(pp[t].x), vl[t], acc);
        }
        out[(size_t)row * HID_N + lane] = acc;
    }
}

extern "C" void kernel_launch(void* const* d_in, const int* in_sizes, int n_in,
                              void* d_out, int out_size, void* d_ws, size_t ws_size,
                              hipStream_t stream) {
    const float* q = (const float*)d_in[0];
    const float* k = (const float*)d_in[1];
    const float* v = (const float*)d_in[2];
    float* out = (float*)d_out;
    const int rows = in_sizes[0] / HID_N;   // N * T_DST = 4096
    tree_attn_kernel<<<(rows + 3) / 4, 256, 0, stream>>>(q, k, v, out);
}

// Round 9
// 233.281 us; speedup vs baseline: 1.0092x; 1.0092x over previous
//
#include <hip/hip_runtime.h>
#include <math.h>

// TreeAttention: hierarchical top-k mask refinement + sparse attention.
// N=8, T_DST=512, T_SRC=4096, HID=64, K=64, W0=64, SCALE_UP=2, OVERSAMPLE=1.5
//
// Round 9: Round 8's latency batching SPILLED (VGPR=64, 155MB scratch
// writes): the backend targeted 8 waves/EU — unreachable, grid gives only
// 4 blocks/CU = 4 waves/EU. Pin waves_per_eu to exactly (4,4) -> 128-VGPR
// budget, batches stay in registers. Otherwise identical to round 8:
//  - dot_f32 loads the whole k row into float4 kr[16] (one waitcnt).
//  - rank loop reads keys in 8-deep uint4 batches.
//  - PV loop reads (p,pix) and v in 8-deep batches.
//  - 4 rows/block, one row per 64-lane wave, private LDS slices,
//    wave_barrier only (no inter-wave sync).

#define TSRC_N 4096
#define HID_N  64
#define NEGV   -32000.0f

__global__ __launch_bounds__(256)
__attribute__((amdgpu_waves_per_eu(4, 4)))
void tree_attn_kernel(const float* __restrict__ q,
                      const float* __restrict__ k,
                      const float* __restrict__ v,
                      float* __restrict__ out)
{
    // wave-uniform wave id (readfirstlane keeps row uniform -> q s_load)
    const int wid  = __builtin_amdgcn_readfirstlane((int)(threadIdx.x >> 6));
    const int lane = threadIdx.x & 63;
    const int row  = (blockIdx.x << 2) + wid;        // 0..4095, wave-uniform
    const int n    = row >> 9;
    const float tsrc = (float)(3585 + (row & 511));

    // per-wave private LDS slices — no cross-wave sharing, no __syncthreads
    __shared__ __align__(16) unsigned int key_s[4][128];
    __shared__ __align__(16) unsigned int bm[4][128];   // 4096-bit bitmaps
    __shared__ int                        pix_s[4][128];
    __shared__ unsigned char              msk_s[4][128];
    __shared__ __align__(8) unsigned int  pp_s[4][128]; // {p_bits, pix} pairs
    unsigned int* const keyw = key_s[wid];
    unsigned int* const bmw  = bm[wid];
    int* const           pixw = pix_s[wid];
    unsigned char* const mskw = msk_s[wid];
    unsigned int* const  ppw  = pp_s[wid];

    const float* qrow = q + (size_t)row * HID_N;     // uniform -> s_load
    const float* kb   = k + (size_t)n * TSRC_N * HID_N;
    const float* vb   = v + (size_t)n * TSRC_N * HID_N;

    // f32 dot: batch-load the whole k row (16x float4 in flight), then FMA.
    auto dot_f32 = [&](int tx) -> float {
        const float4* k4 = (const float4*)(kb + (size_t)tx * HID_N);
        float4 kr[16];
        #pragma unroll
        for (int h = 0; h < 16; ++h) kr[h] = k4[h];   // static idx -> regs
        float a0 = 0.f, a1 = 0.f, a2 = 0.f, a3 = 0.f;
        #pragma unroll
        for (int h = 0; h < 16; ++h) {
            a0 = fmaf(kr[h].x, qrow[h * 4 + 0], a0);
            a1 = fmaf(kr[h].y, qrow[h * 4 + 1], a1);
            a2 = fmaf(kr[h].z, qrow[h * 4 + 2], a2);
            a3 = fmaf(kr[h].w, qrow[h * 4 + 3], a3);
        }
        return (a0 + a1) + (a2 + a3);
    };
    // order-preserving f32 -> u32 flip (key 0 reserved for absent slots)
    auto flip32 = [](float s) -> unsigned int {
        const unsigned int u = __float_as_uint(s);
        return u ^ ((unsigned)((int)u >> 31) | 0x80000000u);
    };

    // iteration 0 state: pixels = arange(96), pmask = arange(96) < 64
    pixw[lane]      = lane;
    pixw[lane + 64] = lane + 64;
    mskw[lane]      = 1;
    mskw[lane + 64] = 0;
    __builtin_amdgcn_wave_barrier();

    float ws = 64.0f;
    int Z = 96;

    for (int it = 0; it < 7; ++it) {
        const bool  last    = (it == 6);
        const float mult    = last ? 1.0f : 1.5f;
        const int   tks_max = (it == 0) ? 63 : (last ? 64 : 96);
        const int   max_z   = last ? 64 : 128;
        const int   e1      = lane + 64;

        // ---- scores -> u32 keys (two elements per lane) ----
        const float r = tsrc / ws;                 // exact f32 (pow2 ratio or 1)
        unsigned int key0 = 0, key1 = 0;
        {
            float s0 = NEGV;
            if (mskw[lane]) {
                int tx = (int)rintf((float)pixw[lane] * r);
                tx = tx < (TSRC_N - 1) ? tx : (TSRC_N - 1);
                s0 = dot_f32(tx);
            }
            key0 = flip32(s0);
        }
        if (e1 < Z) {
            float s1 = NEGV;
            if (mskw[e1]) {
                int tx = (int)rintf((float)pixw[e1] * r);
                tx = tx < (TSRC_N - 1) ? tx : (TSRC_N - 1);
                s1 = dot_f32(tx);
            }
            key1 = flip32(s1);
        }
        keyw[lane] = key0;
        keyw[e1]   = key1;
        bmw[lane]  = 0u;
        bmw[e1]    = 0u;
        __builtin_amdgcn_wave_barrier();

        // ---- ranks: 8-deep batched uint4 key reads, both elements/lane ----
        int r0 = 0, r1 = 0;
        #pragma unroll
        for (int j = 0; j < 128; j += 32) {
            uint4 kk[8];
            #pragma unroll
            for (int t = 0; t < 8; ++t)
                kk[t] = *(const uint4*)&keyw[j + 4 * t];
            #pragma unroll
            for (int t = 0; t < 8; ++t) {
                r0 += (int)(kk[t].x > key0) + (int)(kk[t].y > key0)
                    + (int)(kk[t].z > key0) + (int)(kk[t].w > key0);
                r1 += (int)(kk[t].x > key1) + (int)(kk[t].y > key1)
                    + (int)(kk[t].z > key1) + (int)(kk[t].w > key1);
            }
        }

        // ---- tks = clip(round(ws/tsrc * 64 * mult), 1, min(ws-1, Z-1)) ----
        float x = ws / tsrc;
        x *= 64.0f;
        x *= mult;
        float t = rintf(x);
        t = fmaxf(1.0f, fminf(t, fminf(ws - 1.0f, (float)(Z - 1))));
        const int tks = (int)t;

        const float ws_new = fminf(tsrc, ws * 2.0f);
        const float scale  = ws_new / ws;     // 2.0, tsrc/2048, or 1.0 (exact)

        // ---- scatter next-scale values into the bitmap ----
        if (lane == 0) atomicOr(&bmw[0], 1u); // padded top-k slots -> value 0
        if (r0 < tks_max) {
            const int p  = pixw[lane];
            int s0 = (int)rintf((float)p * scale);
            s0 = s0 < (TSRC_N - 1) ? s0 : (TSRC_N - 1);
            atomicOr(&bmw[s0 >> 5], 1u << (s0 & 31));
            if (r0 < tks) {
                const int s1i = (int)rintf((float)(p + 1) * scale);
                if (s1i - s0 >= 2) {
                    const int c = s0 + 1;
                    atomicOr(&bmw[c >> 5], 1u << (c & 31));
                }
            }
        }
        if (e1 < Z && r1 < tks_max) {
            const int p  = pixw[e1];
            int s0 = (int)rintf((float)p * scale);
            s0 = s0 < (TSRC_N - 1) ? s0 : (TSRC_N - 1);
            atomicOr(&bmw[s0 >> 5], 1u << (s0 & 31));
            if (r1 < tks) {
                const int s1i = (int)rintf((float)(p + 1) * scale);
                if (s1i - s0 >= 2) {
                    const int c = s0 + 1;
                    atomicOr(&bmw[c >> 5], 1u << (c & 31));
                }
            }
        }
        __builtin_amdgcn_wave_barrier();

        // ---- exclusive prefix of popcounts; lane owns words 2L, 2L+1 ----
        const uint2 w2 = *(const uint2*)&bmw[2 * lane];
        const int c = __popc(w2.x) + __popc(w2.y);
        int scan = c;
        #pragma unroll
        for (int off = 1; off < 64; off <<= 1) {
            const int o = __shfl_up(scan, off);
            if (lane >= off) scan += o;
        }
        int pref = scan - c;                  // exclusive prefix
        pixw[lane] = 0;  pixw[e1] = 0;
        mskw[lane] = 0;  mskw[e1] = 0;
        __builtin_amdgcn_wave_barrier();

        // ---- enumerate ascending set bits == sort+dedup, first max_z ----
        unsigned int wv = w2.x;
        int base = lane << 6;                 // word 2L covers values 64L..
        while (wv) {
            if (pref >= max_z) break;
            const int b = __ffs(wv) - 1;
            wv &= wv - 1u;
            pixw[pref] = base + b;
            mskw[pref] = 1;
            ++pref;
        }
        wv = w2.y;
        base += 32;
        while (wv) {
            if (pref >= max_z) break;
            const int b = __ffs(wv) - 1;
            wv &= wv - 1u;
            pixw[pref] = base + b;
            mskw[pref] = 1;
            ++pref;
        }
        __builtin_amdgcn_wave_barrier();

        ws = ws_new;
        Z  = max_z;
    }

    // ---- final attention over the 64 selected pixels (f32, matches ref) ----
    {
        const int pix = pixw[lane];
        float sfin = -1e30f;
        if (mskw[lane]) sfin = dot_f32(pix);
        float m = sfin;
        #pragma unroll
        for (int off = 32; off > 0; off >>= 1)
            m = fmaxf(m, __shfl_xor(m, off));
        const float e = __expf(sfin - m);     // masked -> 0
        float ssum = e;
        #pragma unroll
        for (int off = 32; off > 0; off >>= 1)
            ssum += __shfl_xor(ssum, off);
        const float p = e / ssum;
        ppw[2 * lane]     = __float_as_uint(p);
        ppw[2 * lane + 1] = (unsigned int)pix;
    }
    __builtin_amdgcn_wave_barrier();

    // ---- PV: 8-deep batched (p,pix) + v loads ----
    {
        float acc = 0.f;
        #pragma unroll
        for (int j0 = 0; j0 < 64; j0 += 8) {
            uint2 pp[8];
            #pragma unroll
            for (int t = 0; t < 8; ++t)
                pp[t] = *(const uint2*)&ppw[2 * (j0 + t)];
            float vl[8];
            #pragma unroll
            for (int t = 0; t < 8; ++t)
                vl[t] = vb[(size_t)pp[t].y * HID_N + lane];
            #pragma unroll
            for (int t = 0; t < 8; ++t)
                acc = fmaf(__uint_as_float(pp[t].x), vl[t], acc);
        }
        out[(size_t)row * HID_N + lane] = acc;
    }
}

extern "C" void kernel_launch(void* const* d_in, const int* in_sizes, int n_in,
                              void* d_out, int out_size, void* d_ws, size_t ws_size,
                              hipStream_t stream) {
    const float* q = (const float*)d_in[0];
    const float* k = (const float*)d_in[1];
    const float* v = (const float*)d_in[2];
    float* out = (float*)d_out;
    const int rows = in_sizes[0] / HID_N;   // N * T_DST = 4096
    tree_attn_kernel<<<(rows + 3) / 4, 256, 0, stream>>>(q, k, v, out);
}